// Round 3
// baseline (450.210 us; speedup 1.0000x reference)
//
#include <hip/hip_runtime.h>
#include <cstdint>
#include <cstddef>

typedef __bf16 bf16;
typedef __bf16 bf16x8 __attribute__((ext_vector_type(8)));
typedef float  f32x4  __attribute__((ext_vector_type(4)));

static_assert(sizeof(bf16x8) == 16, "bf16x8 must be 16B");

// async global->LDS, 16B per lane; lane i's data lands at ldsbase + i*16.
__device__ __forceinline__ void async_copy16(const bf16* g, bf16* l) {
  __builtin_amdgcn_global_load_lds(
      (__attribute__((address_space(1))) void*)(g),
      (__attribute__((address_space(3))) void*)(l),
      16, 0, 0);
}

// fp32 -> bf16 bulk convert, 8 elems/thread. n must be a multiple of 2048.
__global__ __launch_bounds__(256)
void conv_f32_bf16(const float* __restrict__ s, bf16* __restrict__ d) {
  const size_t i = ((size_t)blockIdx.x * 256 + threadIdx.x) * 8;
  const f32x4 a = *(const f32x4*)(s + i);
  const f32x4 b = *(const f32x4*)(s + i + 4);
  bf16x8 o;
#pragma unroll
  for (int e = 0; e < 4; ++e) { o[e] = (bf16)a[e]; o[4 + e] = (bf16)b[e]; }
  *(bf16x8*)(d + i) = o;
}

// ---------------------------------------------------------------------------
// 256x256 8-phase GEMM (T2+T3+T4+T5). C[m,n] = sum_k A[m,k]*W[n,k].
// BK=64 split into two K-halves (ks=0,1). LDS per operand: [buf][ks][256][32]
// bf16 -- each K-half is a CONTIGUOUS 16KB block so global_load_lds staging
// (linear dest) works; read swizzle ch = quad ^ ((row>>1)&3) is applied to the
// GLOBAL source (rule #21), giving uniform 8-words/bank ds_read_b128.
// Phase (mh,ks) order (0,0),(1,0),(0,1),(1,1): Kh0 regions read only in
// phases 0-1, Kh1 only in 2-3 => staging tile t+1's Kh1 at phases 0-1
// (other buf) and tile t+2's Kh0 at phases 2-3 (same buf, region just freed)
// is race-free given the per-phase barrier pairs. ONE vmcnt(4) per K-tile
// (phase 3): everything except the newest 2 half-tiles (Kh0(t+2)) has landed
// => tile t+1 fully resident. Loads get ~6 phases of flight time.
// ---------------------------------------------------------------------------
template<int AMODE>
__device__ __forceinline__ void stage_half(const bf16* __restrict__ P, int K,
                                           int row0, int k0, int ks,
                                           bf16* lds, int wave, int lane) {
  // one K-half: 256 rows x 32 cols = 16KB = 2 instrs (512 thr x 16B)
#pragma unroll
  for (int i = 0; i < 2; ++i) {
    const int lin0 = i * 512 + wave * 64;   // wave-uniform
    const int lin  = lin0 + lane;
    const int row  = lin >> 2;              // 0..255
    const int ch   = lin & 3;
    const int gch  = ch ^ ((row >> 1) & 3); // pre-swizzled global source
    const bf16* src;
    if constexpr (AMODE == 2) {
      const int rowA = row0 + row;
      const int b = rowA >> 11, s = rowA & 2047;
      const int kk = k0 + ks * 32;
      src = P + ((size_t)(b * 16 + (kk >> 7)) * 2048 + s) * 128 + (kk & 127) + gch * 8;
    } else {
      src = P + (size_t)(row0 + row) * K + k0 + ks * 32 + gch * 8;
    }
    async_copy16(src, lds + ks * 8192 + lin0 * 8);
  }
}

// AMODE 0: A row-major [M,K].  AMODE 2: A gathered from [B,H,S,D] plane.
// CMODE 0: C fp32 row-major.  CMODE 1: scattered bf16 (Q/K planes + Vt
// transposed), global col = nbase + n, same scatter rule as before.
template<int AMODE, int CMODE>
__global__ __launch_bounds__(512, 2)
void gemm256(const bf16* __restrict__ A, const bf16* __restrict__ W,
             float* __restrict__ Crow, bf16* __restrict__ Cq,
             bf16* __restrict__ Ck, bf16* __restrict__ Cvt,
             int M, int N, int K, int nbase) {
  __shared__ bf16 As[2 * 16384];   // [buf][ks][256][32]
  __shared__ bf16 Ws[2 * 16384];

  const int tid  = threadIdx.x;
  const int wave = tid >> 6, lane = tid & 63;
  const int quad = lane >> 4, r = lane & 15;
  const int wr = wave >> 2, wc = wave & 3;   // 2M x 4N wave grid

  // XCD-aware bijective swizzle (all our launches have nwg % 8 == 0)
  const int gx  = gridDim.x;
  const int nwg = gx * gridDim.y;
  int wg = blockIdx.y * gx + blockIdx.x;
  wg = (wg & 7) * (nwg >> 3) + (wg >> 3);
  const int m0 = (wg / gx) * 256;
  const int n0 = (wg % gx) * 256;

  const int wm = wr * 128;
  const int wn = wc * 64;
  const int nT = K >> 6;

  f32x4 acc[8][4] = {};

  // prologue stream: AKh0(0) BKh0(0) AKh1(0) BKh1(0) AKh0(1) BKh0(1)
  stage_half<AMODE>(A, K, m0, 0, 0, As, wave, lane);
  stage_half<0>   (W, K, n0, 0, 0, Ws, wave, lane);
  stage_half<AMODE>(A, K, m0, 0, 1, As, wave, lane);
  stage_half<0>   (W, K, n0, 0, 1, Ws, wave, lane);
  if (nT > 1) {
    stage_half<AMODE>(A, K, m0, 64, 0, As + 16384, wave, lane);
    stage_half<0>   (W, K, n0, 64, 0, Ws + 16384, wave, lane);
    asm volatile("s_waitcnt vmcnt(4)" ::: "memory");   // tile 0 resident
  } else {
    asm volatile("s_waitcnt vmcnt(0)" ::: "memory");
  }
  __builtin_amdgcn_s_barrier();

  for (int t = 0; t < nT; ++t) {
    const int c = t & 1;
    bf16* Ab = As + c * 16384;
    bf16* Wb = Ws + c * 16384;
    bf16* An = As + (c ^ 1) * 16384;
    bf16* Wn = Ws + (c ^ 1) * 16384;
    bf16x8 af[4], bfr[4];
#pragma unroll
    for (int ph = 0; ph < 4; ++ph) {
      const int ks = ph >> 1, mh = ph & 1;
      if (mh == 0) {
#pragma unroll
        for (int n = 0; n < 4; ++n) {
          const int br = wn + n * 16 + r;
          bfr[n] = *(const bf16x8*)(Wb + ks * 8192 + br * 32 + ((quad ^ ((br >> 1) & 3)) << 3));
        }
      }
#pragma unroll
      for (int m = 0; m < 4; ++m) {
        const int ar = wm + mh * 64 + m * 16 + r;
        af[m] = *(const bf16x8*)(Ab + ks * 8192 + ar * 32 + ((quad ^ ((ar >> 1) & 3)) << 3));
      }
      // staging schedule (1 half-tile per phase, per slot-lifetime analysis)
      if (ph == 0) {
        if (t + 1 < nT) stage_half<AMODE>(A, K, m0, (t + 1) << 6, 1, An, wave, lane);
      } else if (ph == 1) {
        if (t + 1 < nT) stage_half<0>(W, K, n0, (t + 1) << 6, 1, Wn, wave, lane);
      } else if (ph == 2) {
        if (t + 2 < nT) stage_half<AMODE>(A, K, m0, (t + 2) << 6, 0, Ab, wave, lane);
      } else {
        if (t + 2 < nT) {
          stage_half<0>(W, K, n0, (t + 2) << 6, 0, Wb, wave, lane);
          __builtin_amdgcn_sched_barrier(0);
          asm volatile("s_waitcnt vmcnt(4)" ::: "memory");  // tile t+1 resident
        } else if (t + 1 < nT) {
          __builtin_amdgcn_sched_barrier(0);
          asm volatile("s_waitcnt vmcnt(0)" ::: "memory");  // tail drain
        }
      }
      __builtin_amdgcn_s_barrier();
      asm volatile("s_waitcnt lgkmcnt(0)" ::: "memory");
      __builtin_amdgcn_sched_barrier(0);
      __builtin_amdgcn_s_setprio(1);
#pragma unroll
      for (int m = 0; m < 4; ++m)
#pragma unroll
        for (int n = 0; n < 4; ++n)
          acc[mh * 4 + m][n] =
              __builtin_amdgcn_mfma_f32_16x16x32_bf16(af[m], bfr[n], acc[mh * 4 + m][n], 0, 0, 0);
      __builtin_amdgcn_s_setprio(0);
      __builtin_amdgcn_s_barrier();
    }
  }

  // C-layout: row = quad*4+reg, col = lane&15 (m89-verified).
#pragma unroll
  for (int i = 0; i < 8; ++i) {
    const int growb = m0 + wm + i * 16 + quad * 4;
#pragma unroll
    for (int j = 0; j < 4; ++j) {
      const int gcol = n0 + wn + j * 16 + r;
#pragma unroll
      for (int rg = 0; rg < 4; ++rg) {
        const int grow = growb + rg;
        if constexpr (CMODE == 1) {
          const int gc = nbase + gcol;
          const int which = gc >> 11;
          const int h = (gc >> 7) & 15;
          const int d = gc & 127;
          const int b = grow >> 11;
          const int s = grow & 2047;
          const bf16 v = (bf16)acc[i][j][rg];
          if (which == 0)
            Cq[(((size_t)b * 16 + h) * 2048 + s) * 128 + d] = v;
          else if (which == 1)
            Ck[(((size_t)b * 16 + h) * 2048 + s) * 128 + d] = v;
          else
            Cvt[(((size_t)b * 16 + h) * 128 + d) * 2048 + s] = v;  // transposed
        } else {
          Crow[(size_t)grow * N + gcol] = acc[i][j][rg];
        }
      }
    }
  }
}

// Flash attention, causal (unchanged from R2). Q,K: [B*H, S, 128] bf16;
// Vt: [B*H, 128, S] bf16. O written IN-PLACE into the Q plane.
__global__ __launch_bounds__(512, 2)
void attn_kernel(bf16* __restrict__ Q, const bf16* __restrict__ K,
                 const bf16* __restrict__ Vt, int S) {
  __shared__ bf16 k_lds[2][64 * 128];   // [kv][d], swizzled
  __shared__ bf16 v_lds[2][128 * 64];   // [d][kv], swizzled
  __shared__ bf16 p_lds[8][16 * 64];    // per-wave P [qrow][kv], swizzled

  const int tid = threadIdx.x, wave = tid >> 6, lane = tid & 63;
  const int quad = lane >> 4, r = lane & 15;
  const int bh = blockIdx.y;
  bf16* Qh = Q + (size_t)bh * S * 128;
  const bf16* Kh = K + (size_t)bh * S * 128;
  const bf16* Vth = Vt + (size_t)bh * 128 * S;

  const float sc = 0.0883883476483184f * 1.4426950408889634f; // 1/sqrt(128)*log2e

  auto issue_stage = [&](int kv0, int buf) {
#pragma unroll
    for (int j = 0; j < 2; ++j) {
      const int lin0 = j * 512 + wave * 64;       // wave-uniform
      const int lin = lin0 + lane;
      const int row = lin >> 4, ch = lin & 15;    // K: [64 kv][16 chunks]
      async_copy16(Kh + (size_t)(kv0 + row) * 128 + ((ch ^ (row & 7)) << 3),
                   &k_lds[buf][0] + lin0 * 8);
    }
#pragma unroll
    for (int j = 0; j < 2; ++j) {
      const int lin0 = j * 512 + wave * 64;
      const int lin = lin0 + lane;
      const int row = lin >> 3, c = lin & 7;      // V^T: [128 d][8 chunks]
      async_copy16(Vth + (size_t)row * S + kv0 + ((c ^ (row & 7)) << 3),
                   &v_lds[buf][0] + lin0 * 8);
    }
  };

  for (int pass = 0; pass < 2; ++pass) {
    const int qb = pass ? blockIdx.x : (15 - blockIdx.x);  // heavy tile first
    const int q0 = qb << 7;
    const int qrow0 = q0 + wave * 16;   // 16 q-rows per wave
    const int nkv = (q0 + 128) >> 6;

    bf16x8 qf[4];
    for (int ks = 0; ks < 4; ++ks)
      qf[ks] = *(const bf16x8*)(Qh + (size_t)(qrow0 + r) * 128 + ks * 32 + quad * 8);

    f32x4 o_acc[8] = {};
    f32x4 m_run, l_run;
    for (int t = 0; t < 4; ++t) { m_run[t] = -1e30f; l_run[t] = 0.f; }

    issue_stage(0, 0);

    for (int kt = 0; kt < nkv; ++kt) {
      const int kv0 = kt << 6;
      const int cur = kt & 1;
      if (kt + 1 < nkv) {
        issue_stage((kt + 1) << 6, cur ^ 1);
        asm volatile("s_waitcnt vmcnt(4)" ::: "memory");
      } else {
        asm volatile("s_waitcnt vmcnt(0)" ::: "memory");
      }
      __builtin_amdgcn_sched_barrier(0);
      __syncthreads();

      if (kv0 <= qrow0 + 15) {
        f32x4 sa[4] = {};
        __builtin_amdgcn_s_setprio(1);
        for (int ks = 0; ks < 4; ++ks) {
          bf16x8 kf[4];
          for (int nt = 0; nt < 4; ++nt) {
            const int kr = nt * 16 + r;
            kf[nt] = *(const bf16x8*)(&k_lds[cur][0] + kr * 128 + (((ks * 4 + quad) ^ (kr & 7)) << 3));
          }
          for (int nt = 0; nt < 4; ++nt)
            sa[nt] = __builtin_amdgcn_mfma_f32_16x16x32_bf16(qf[ks], kf[nt], sa[nt], 0, 0, 0);
        }
        __builtin_amdgcn_s_setprio(0);
        if (kv0 + 63 > qrow0) {
          for (int nt = 0; nt < 4; ++nt) {
            const int col  = kv0 + nt * 16 + r;
            const int rowb = qrow0 + quad * 4;
            for (int rg = 0; rg < 4; ++rg)
              if (col > rowb + rg) sa[nt][rg] = -1e30f;
          }
        }
        f32x4 mx = sa[0];
        for (int nt = 1; nt < 4; ++nt)
          for (int rg = 0; rg < 4; ++rg) mx[rg] = fmaxf(mx[rg], sa[nt][rg]);
        for (int off = 1; off < 16; off <<= 1)
          for (int rg = 0; rg < 4; ++rg) mx[rg] = fmaxf(mx[rg], __shfl_xor(mx[rg], off, 64));
        float need = mx[0] - m_run[0];
        for (int rg = 1; rg < 4; ++rg) need = fmaxf(need, mx[rg] - m_run[rg]);
        if (need * sc > 8.0f) {
          f32x4 alpha;
          for (int rg = 0; rg < 4; ++rg) {
            const float mnew = fmaxf(m_run[rg], mx[rg]);
            alpha[rg] = exp2f((m_run[rg] - mnew) * sc);
            m_run[rg] = mnew;
            l_run[rg] *= alpha[rg];
          }
          for (int nt2 = 0; nt2 < 8; ++nt2)
            for (int rg = 0; rg < 4; ++rg) o_acc[nt2][rg] *= alpha[rg];
        }
        f32x4 rsum = {0.f, 0.f, 0.f, 0.f};
        for (int nt = 0; nt < 4; ++nt)
          for (int rg = 0; rg < 4; ++rg) {
            const float p = exp2f((sa[nt][rg] - m_run[rg]) * sc);
            sa[nt][rg] = p;
            rsum[rg] += p;
          }
        for (int off = 1; off < 16; off <<= 1)
          for (int rg = 0; rg < 4; ++rg) rsum[rg] += __shfl_xor(rsum[rg], off, 64);
        for (int rg = 0; rg < 4; ++rg) l_run[rg] += rsum[rg];
        for (int nt = 0; nt < 4; ++nt)
          for (int rg = 0; rg < 4; ++rg) {
            const int prow = quad * 4 + rg;
            const int pcol = nt * 16 + r;
            p_lds[wave][prow * 64 + (((pcol >> 3) ^ (prow & 7)) * 8) + (pcol & 7)] =
                (bf16)sa[nt][rg];
          }
        __builtin_amdgcn_s_setprio(1);
        for (int ks2 = 0; ks2 < 2; ++ks2) {
          const int prow = r;
          const bf16x8 pf = *(const bf16x8*)(p_lds[wave] + prow * 64 + (((ks2 * 4 + quad) ^ (prow & 7)) * 8));
          for (int nt2 = 0; nt2 < 8; ++nt2) {
            const int vrow = nt2 * 16 + r;
            const bf16x8 vf = *(const bf16x8*)(&v_lds[cur][0] + vrow * 64 + (((ks2 * 4 + quad) ^ (vrow & 7)) * 8));
            o_acc[nt2] = __builtin_amdgcn_mfma_f32_16x16x32_bf16(pf, vf, o_acc[nt2], 0, 0, 0);
          }
        }
        __builtin_amdgcn_s_setprio(0);
      }
      __syncthreads();
    }

    f32x4 inv;
    for (int rg = 0; rg < 4; ++rg) inv[rg] = 1.0f / l_run[rg];
    for (int nt2 = 0; nt2 < 8; ++nt2) {
      const int d = nt2 * 16 + r;
      for (int rg = 0; rg < 4; ++rg) {
        const int s = qrow0 + quad * 4 + rg;
        Qh[(size_t)s * 128 + d] = (bf16)(o_acc[nt2][rg] * inv[rg]);
      }
    }
  }
}

extern "C" void kernel_launch(void* const* d_in, const int* in_sizes, int n_in,
                              void* d_out, int out_size, void* d_ws, size_t ws_size,
                              hipStream_t stream) {
  const float* x     = (const float*)d_in[0];   // [2,2048,2048] fp32
  const float* Wqkv  = (const float*)d_in[1];   // [6144,2048] fp32
  const float* Wproj = (const float*)d_in[2];   // [2048,2048] fp32
  float* out = (float*)d_out;                   // [2,2048,2048] fp32 = 32 MiB

  const int Bm = 4096, E = 2048;
  const size_t plane = 8388608;                 // 16 MiB as bf16

  // ws (48 MiB): [0,plane) Q plane; [plane,2p) V^T plane; [2p,3p) xb then Wproj_bf16.
  // d_out (32 MiB): [0,plane) bf16 K plane; [plane,+6291456) bf16 Wqkv half;
  //   both dead before proj GEMM overwrites d_out with fp32 output.
  bf16* qw  = (bf16*)d_ws;
  bf16* vtw = qw + plane;
  bf16* xb  = vtw + plane;       // later reused for Wproj bf16
  bf16* kw  = (bf16*)d_out;
  bf16* wqb = kw + plane;        // 6291456 elems = 12 MiB, fits in d_out upper half

  // 1) x -> bf16
  conv_f32_bf16<<<8388608 / 2048, 256, 0, stream>>>(x, xb);
  // 2) Wqkv rows [0,3072) -> bf16
  conv_f32_bf16<<<6291456 / 2048, 256, 0, stream>>>(Wqkv, wqb);
  // 3) QKV GEMM chunk A: n in [0,3072) -> all Q + K heads 0..7
  gemm256<0, 1><<<dim3(3072 / 256, Bm / 256), 512, 0, stream>>>(
      xb, wqb, nullptr, qw, kw, vtw, Bm, 3072, E, 0);
  // 4) Wqkv rows [3072,6144) -> bf16 (overwrites wqb after chunk A)
  conv_f32_bf16<<<6291456 / 2048, 256, 0, stream>>>(Wqkv + 6291456, wqb);
  // 5) QKV GEMM chunk B: n in [3072,6144) -> K heads 8..15 + all V (transposed)
  gemm256<0, 1><<<dim3(3072 / 256, Bm / 256), 512, 0, stream>>>(
      xb, wqb, nullptr, qw, kw, vtw, Bm, 3072, E, 3072);
  // 6) attention (O overwrites Q plane); paired causal blocks, 8 waves/block
  attn_kernel<<<dim3(8, 32), 512, 0, stream>>>(qw, kw, vtw, 2048);
  // 7) Wproj -> bf16 (xb region; xb dead)
  conv_f32_bf16<<<4194304 / 2048, 256, 0, stream>>>(Wproj, xb);
  // 8) proj GEMM: A = O plane (gather), C = d_out fp32
  gemm256<2, 0><<<dim3(2048 / 256, Bm / 256), 512, 0, stream>>>(
      qw, xb, out, nullptr, nullptr, nullptr, Bm, 2048, E, 0);
}

// Round 4
// 413.523 us; speedup vs baseline: 1.0887x; 1.0887x over previous
//
#include <hip/hip_runtime.h>
#include <cstdint>
#include <cstddef>

typedef __bf16 bf16;
typedef __bf16 bf16x8 __attribute__((ext_vector_type(8)));
typedef float  f32x4  __attribute__((ext_vector_type(4)));

static_assert(sizeof(bf16x8) == 16, "bf16x8 must be 16B");

// async global->LDS, 16B per lane; lane i's data lands at ldsbase + i*16.
__device__ __forceinline__ void async_copy16(const bf16* g, bf16* l) {
  __builtin_amdgcn_global_load_lds(
      (__attribute__((address_space(1))) void*)(g),
      (__attribute__((address_space(3))) void*)(l),
      16, 0, 0);
}

__device__ __forceinline__ uint32_t lds_u32(const bf16* p) {
  return (uint32_t)(uintptr_t)((__attribute__((address_space(3))) const bf16*)p);
}

// fp32 -> bf16 bulk convert, 8 elems/thread. n must be a multiple of 2048.
__global__ __launch_bounds__(256)
void conv_f32_bf16(const float* __restrict__ s, bf16* __restrict__ d) {
  const size_t i = ((size_t)blockIdx.x * 256 + threadIdx.x) * 8;
  const f32x4 a = *(const f32x4*)(s + i);
  const f32x4 b = *(const f32x4*)(s + i + 4);
  bf16x8 o;
#pragma unroll
  for (int e = 0; e < 4; ++e) { o[e] = (bf16)a[e]; o[4 + e] = (bf16)b[e]; }
  *(bf16x8*)(d + i) = o;
}

// ---------------------------------------------------------------------------
// 128(M) x 256(N) 2-phase-per-K-tile GEMM, BK=64, 512 threads (8 waves 2Mx4N,
// wave tile 64x64 -> acc[4][4] = 64 VGPRs). C[m,n] = sum_k A[m,k]*W[n,k].
// LDS: As[2buf][2ks][128][32] (32KB) + Ws[2][2][256][32] (64KB) = 96KB.
// Staging: global_load_lds, linear dest, swizzle on GLOBAL source (rule #21):
// LDS[row][ch] = G[row][ch ^ ((row>>1)&3)]; read chunk cs = quad ^ ((r>>1)&3)
// (row+16 invariant -> fragment reads are base + offset:1024*i immediates).
// Counted-vmcnt ledger (T3+T4): 3 load-instrs/thread staged per phase
// (A-half 1 + W-half 2); ph0(t) stages Kh1(t+1)->buf^1, ph1(t) stages
// Kh0(t+2)->buf (region freed at ph0(t)). vmcnt(6) at EVERY phase end
// protects the next phase's reads (2 staged phases = 6 instrs in flight);
// tails 3/0. Fragment reads via asm ds_read_b128 so the compiler cannot
// legalize with its own vmcnt-before-ds_read (R3 suspect); manual
// lgkmcnt(0)+sched_barrier(0) before MFMA per rule #18.
// ---------------------------------------------------------------------------
template<int AMODE>
__device__ __forceinline__ void stageA(const bf16* __restrict__ P, int K,
                                       int row0, int k0, int ks,
                                       bf16* lds, int wave, int lane) {
  const int lin0 = wave * 64;           // wave-uniform
  const int lin  = lin0 + lane;
  const int row  = lin >> 2;            // 0..127
  const int ch   = lin & 3;
  const int gch  = ch ^ ((row >> 1) & 3);
  const bf16* src;
  if constexpr (AMODE == 2) {
    const int rowA = row0 + row;
    const int b = rowA >> 11, s = rowA & 2047;
    const int kk = k0 + ks * 32;
    src = P + ((size_t)(b * 16 + (kk >> 7)) * 2048 + s) * 128 + (kk & 127) + gch * 8;
  } else {
    src = P + (size_t)(row0 + row) * K + k0 + ks * 32 + gch * 8;
  }
  async_copy16(src, lds + ks * 4096 + lin0 * 8);
}

__device__ __forceinline__ void stageW(const bf16* __restrict__ P, int K,
                                       int row0, int k0, int ks,
                                       bf16* lds, int wave, int lane) {
#pragma unroll
  for (int i = 0; i < 2; ++i) {
    const int lin0 = i * 512 + wave * 64;
    const int lin  = lin0 + lane;
    const int row  = lin >> 2;          // 0..255
    const int ch   = lin & 3;
    const int gch  = ch ^ ((row >> 1) & 3);
    async_copy16(P + (size_t)(row0 + row) * K + k0 + ks * 32 + gch * 8,
                 lds + ks * 8192 + lin0 * 8);
  }
}

__device__ __forceinline__ void ld_frags(uint32_t ab, uint32_t bb,
                                         bf16x8 (&a)[4], bf16x8 (&b)[4]) {
  asm volatile("ds_read_b128 %0, %1 offset:0"    : "=v"(a[0]) : "v"(ab));
  asm volatile("ds_read_b128 %0, %1 offset:1024" : "=v"(a[1]) : "v"(ab));
  asm volatile("ds_read_b128 %0, %1 offset:2048" : "=v"(a[2]) : "v"(ab));
  asm volatile("ds_read_b128 %0, %1 offset:3072" : "=v"(a[3]) : "v"(ab));
  asm volatile("ds_read_b128 %0, %1 offset:0"    : "=v"(b[0]) : "v"(bb));
  asm volatile("ds_read_b128 %0, %1 offset:1024" : "=v"(b[1]) : "v"(bb));
  asm volatile("ds_read_b128 %0, %1 offset:2048" : "=v"(b[2]) : "v"(bb));
  asm volatile("ds_read_b128 %0, %1 offset:3072" : "=v"(b[3]) : "v"(bb));
}

// AMODE 0: A row-major [M,K].  AMODE 2: A gathered from [B,H,S,D] plane.
// CMODE 0: C fp32 row-major -> Crow.
// CMODE 1: C scattered bf16; global col = nbase+n: <2048 -> Cq[b,h,s,d],
//          <4096 -> Ck[b,h,s,d], else -> Cvt TRANSPOSED [b,h,d,s].
template<int AMODE, int CMODE>
__global__ __launch_bounds__(512, 2)
void gemm_bt2(const bf16* __restrict__ A, const bf16* __restrict__ W,
              float* __restrict__ Crow, bf16* __restrict__ Cq,
              bf16* __restrict__ Ck, bf16* __restrict__ Cvt,
              int M, int N, int K, int nbase) {
  __shared__ bf16 As[2][2][128 * 32];
  __shared__ bf16 Ws[2][2][256 * 32];

  const int tid  = threadIdx.x;
  const int wave = tid >> 6, lane = tid & 63;
  const int quad = lane >> 4, r = lane & 15;
  const int wr = wave >> 2, wc = wave & 3;   // 2M x 4N wave grid

  // XCD-aware bijective swizzle (nwg = 256 for all our launches, %8==0)
  const int gx  = gridDim.x;
  const int nwg = gx * gridDim.y;
  int wg = blockIdx.y * gx + blockIdx.x;
  wg = (wg & 7) * (nwg >> 3) + (wg >> 3);
  const int m0 = (wg / gx) * 128;
  const int n0 = (wg % gx) * 256;

  const int wm = wr * 64, wn = wc * 64;
  const int nT = K >> 6;
  const int cs = quad ^ ((r >> 1) & 3);      // read chunk (A and W)

  f32x4 acc[4][4] = {};

  const uint32_t a_rd = lds_u32(&As[0][0][0]) + (((wm + r) * 32 + cs * 8) << 1);
  const uint32_t b_rd = lds_u32(&Ws[0][0][0]) + (((wn + r) * 32 + cs * 8) << 1);

  // prologue: Kh0(0), Kh1(0), Kh0(1)
  stageA<AMODE>(A, K, m0, 0, 0, &As[0][0][0], wave, lane);
  stageW(W, K, n0, 0, 0, &Ws[0][0][0], wave, lane);
  stageA<AMODE>(A, K, m0, 0, 1, &As[0][0][0], wave, lane);
  stageW(W, K, n0, 0, 1, &Ws[0][0][0], wave, lane);
  if (nT > 1) {
    stageA<AMODE>(A, K, m0, 64, 0, &As[1][0][0], wave, lane);
    stageW(W, K, n0, 64, 0, &Ws[1][0][0], wave, lane);
    asm volatile("s_waitcnt vmcnt(6)" ::: "memory");   // Kh0(0) resident
  } else {
    asm volatile("s_waitcnt vmcnt(3)" ::: "memory");
  }
  __builtin_amdgcn_s_barrier();

  for (int t = 0; t < nT; ++t) {
    const int c = t & 1;
    bf16x8 af[4], bw[4];

    // ---- phase ks=0: reads buf c ks0; stages Kh1(t+1) -> buf^1 ----
    ld_frags(a_rd + (c * 2 + 0) * 8192, b_rd + (c * 2 + 0) * 16384, af, bw);
    if (t + 1 < nT) {
      stageA<AMODE>(A, K, m0, (t + 1) << 6, 1, &As[c ^ 1][0][0], wave, lane);
      stageW(W, K, n0, (t + 1) << 6, 1, &Ws[c ^ 1][0][0], wave, lane);
      asm volatile("s_waitcnt vmcnt(6)" ::: "memory");  // Kh1(t) resident
    } else {
      asm volatile("s_waitcnt vmcnt(0)" ::: "memory");
    }
    __builtin_amdgcn_sched_barrier(0);
    __builtin_amdgcn_s_barrier();
    asm volatile("s_waitcnt lgkmcnt(0)" ::: "memory");
    __builtin_amdgcn_sched_barrier(0);
    __builtin_amdgcn_s_setprio(1);
#pragma unroll
    for (int m = 0; m < 4; ++m)
#pragma unroll
      for (int n = 0; n < 4; ++n)
        acc[m][n] = __builtin_amdgcn_mfma_f32_16x16x32_bf16(af[m], bw[n], acc[m][n], 0, 0, 0);
    __builtin_amdgcn_s_setprio(0);
    __builtin_amdgcn_s_barrier();

    // ---- phase ks=1: reads buf c ks1; stages Kh0(t+2) -> buf c ----
    ld_frags(a_rd + (c * 2 + 1) * 8192, b_rd + (c * 2 + 1) * 16384, af, bw);
    if (t + 2 < nT) {
      stageA<AMODE>(A, K, m0, (t + 2) << 6, 0, &As[c][0][0], wave, lane);
      stageW(W, K, n0, (t + 2) << 6, 0, &Ws[c][0][0], wave, lane);
      asm volatile("s_waitcnt vmcnt(6)" ::: "memory");  // Kh0(t+1) resident
    } else if (t + 1 < nT) {
      asm volatile("s_waitcnt vmcnt(3)" ::: "memory");
    } else {
      asm volatile("s_waitcnt vmcnt(0)" ::: "memory");
    }
    __builtin_amdgcn_sched_barrier(0);
    __builtin_amdgcn_s_barrier();
    asm volatile("s_waitcnt lgkmcnt(0)" ::: "memory");
    __builtin_amdgcn_sched_barrier(0);
    __builtin_amdgcn_s_setprio(1);
#pragma unroll
    for (int m = 0; m < 4; ++m)
#pragma unroll
      for (int n = 0; n < 4; ++n)
        acc[m][n] = __builtin_amdgcn_mfma_f32_16x16x32_bf16(af[m], bw[n], acc[m][n], 0, 0, 0);
    __builtin_amdgcn_s_setprio(0);
    __builtin_amdgcn_s_barrier();
  }

  // C-layout: row = quad*4+reg, col = lane&15 (m89-verified).
#pragma unroll
  for (int i = 0; i < 4; ++i) {
    const int growb = m0 + wm + i * 16 + quad * 4;
#pragma unroll
    for (int j = 0; j < 4; ++j) {
      const int gcol = n0 + wn + j * 16 + r;
#pragma unroll
      for (int rg = 0; rg < 4; ++rg) {
        const int grow = growb + rg;
        if constexpr (CMODE == 1) {
          const int gc = nbase + gcol;
          const int which = gc >> 11;
          const int h = (gc >> 7) & 15;
          const int d = gc & 127;
          const int b = grow >> 11;
          const int s = grow & 2047;
          const bf16 v = (bf16)acc[i][j][rg];
          if (which == 0)
            Cq[(((size_t)b * 16 + h) * 2048 + s) * 128 + d] = v;
          else if (which == 1)
            Ck[(((size_t)b * 16 + h) * 2048 + s) * 128 + d] = v;
          else
            Cvt[(((size_t)b * 16 + h) * 128 + d) * 2048 + s] = v;  // transposed
        } else {
          Crow[(size_t)grow * N + gcol] = acc[i][j][rg];
        }
      }
    }
  }
}

// Flash attention, causal (unchanged from R2). Q,K: [B*H, S, 128] bf16;
// Vt: [B*H, 128, S] bf16. O written IN-PLACE into the Q plane.
__global__ __launch_bounds__(512, 2)
void attn_kernel(bf16* __restrict__ Q, const bf16* __restrict__ K,
                 const bf16* __restrict__ Vt, int S) {
  __shared__ bf16 k_lds[2][64 * 128];   // [kv][d], swizzled
  __shared__ bf16 v_lds[2][128 * 64];   // [d][kv], swizzled
  __shared__ bf16 p_lds[8][16 * 64];    // per-wave P [qrow][kv], swizzled

  const int tid = threadIdx.x, wave = tid >> 6, lane = tid & 63;
  const int quad = lane >> 4, r = lane & 15;
  const int bh = blockIdx.y;
  bf16* Qh = Q + (size_t)bh * S * 128;
  const bf16* Kh = K + (size_t)bh * S * 128;
  const bf16* Vth = Vt + (size_t)bh * 128 * S;

  const float sc = 0.0883883476483184f * 1.4426950408889634f; // 1/sqrt(128)*log2e

  auto issue_stage = [&](int kv0, int buf) {
#pragma unroll
    for (int j = 0; j < 2; ++j) {
      const int lin0 = j * 512 + wave * 64;       // wave-uniform
      const int lin = lin0 + lane;
      const int row = lin >> 4, ch = lin & 15;    // K: [64 kv][16 chunks]
      async_copy16(Kh + (size_t)(kv0 + row) * 128 + ((ch ^ (row & 7)) << 3),
                   &k_lds[buf][0] + lin0 * 8);
    }
#pragma unroll
    for (int j = 0; j < 2; ++j) {
      const int lin0 = j * 512 + wave * 64;
      const int lin = lin0 + lane;
      const int row = lin >> 3, c = lin & 7;      // V^T: [128 d][8 chunks]
      async_copy16(Vth + (size_t)row * S + kv0 + ((c ^ (row & 7)) << 3),
                   &v_lds[buf][0] + lin0 * 8);
    }
  };

  for (int pass = 0; pass < 2; ++pass) {
    const int qb = pass ? blockIdx.x : (15 - blockIdx.x);  // heavy tile first
    const int q0 = qb << 7;
    const int qrow0 = q0 + wave * 16;   // 16 q-rows per wave
    const int nkv = (q0 + 128) >> 6;

    bf16x8 qf[4];
    for (int ks = 0; ks < 4; ++ks)
      qf[ks] = *(const bf16x8*)(Qh + (size_t)(qrow0 + r) * 128 + ks * 32 + quad * 8);

    f32x4 o_acc[8] = {};
    f32x4 m_run, l_run;
    for (int t = 0; t < 4; ++t) { m_run[t] = -1e30f; l_run[t] = 0.f; }

    issue_stage(0, 0);

    for (int kt = 0; kt < nkv; ++kt) {
      const int kv0 = kt << 6;
      const int cur = kt & 1;
      if (kt + 1 < nkv) {
        issue_stage((kt + 1) << 6, cur ^ 1);
        asm volatile("s_waitcnt vmcnt(4)" ::: "memory");
      } else {
        asm volatile("s_waitcnt vmcnt(0)" ::: "memory");
      }
      __builtin_amdgcn_sched_barrier(0);
      __syncthreads();

      if (kv0 <= qrow0 + 15) {
        f32x4 sa[4] = {};
        __builtin_amdgcn_s_setprio(1);
        for (int ks = 0; ks < 4; ++ks) {
          bf16x8 kf[4];
          for (int nt = 0; nt < 4; ++nt) {
            const int kr = nt * 16 + r;
            kf[nt] = *(const bf16x8*)(&k_lds[cur][0] + kr * 128 + (((ks * 4 + quad) ^ (kr & 7)) << 3));
          }
          for (int nt = 0; nt < 4; ++nt)
            sa[nt] = __builtin_amdgcn_mfma_f32_16x16x32_bf16(qf[ks], kf[nt], sa[nt], 0, 0, 0);
        }
        __builtin_amdgcn_s_setprio(0);
        if (kv0 + 63 > qrow0) {
          for (int nt = 0; nt < 4; ++nt) {
            const int col  = kv0 + nt * 16 + r;
            const int rowb = qrow0 + quad * 4;
            for (int rg = 0; rg < 4; ++rg)
              if (col > rowb + rg) sa[nt][rg] = -1e30f;
          }
        }
        f32x4 mx = sa[0];
        for (int nt = 1; nt < 4; ++nt)
          for (int rg = 0; rg < 4; ++rg) mx[rg] = fmaxf(mx[rg], sa[nt][rg]);
        for (int off = 1; off < 16; off <<= 1)
          for (int rg = 0; rg < 4; ++rg) mx[rg] = fmaxf(mx[rg], __shfl_xor(mx[rg], off, 64));
        float need = mx[0] - m_run[0];
        for (int rg = 1; rg < 4; ++rg) need = fmaxf(need, mx[rg] - m_run[rg]);
        if (need * sc > 8.0f) {
          f32x4 alpha;
          for (int rg = 0; rg < 4; ++rg) {
            const float mnew = fmaxf(m_run[rg], mx[rg]);
            alpha[rg] = exp2f((m_run[rg] - mnew) * sc);
            m_run[rg] = mnew;
            l_run[rg] *= alpha[rg];
          }
          for (int nt2 = 0; nt2 < 8; ++nt2)
            for (int rg = 0; rg < 4; ++rg) o_acc[nt2][rg] *= alpha[rg];
        }
        f32x4 rsum = {0.f, 0.f, 0.f, 0.f};
        for (int nt = 0; nt < 4; ++nt)
          for (int rg = 0; rg < 4; ++rg) {
            const float p = exp2f((sa[nt][rg] - m_run[rg]) * sc);
            sa[nt][rg] = p;
            rsum[rg] += p;
          }
        for (int off = 1; off < 16; off <<= 1)
          for (int rg = 0; rg < 4; ++rg) rsum[rg] += __shfl_xor(rsum[rg], off, 64);
        for (int rg = 0; rg < 4; ++rg) l_run[rg] += rsum[rg];
        for (int nt = 0; nt < 4; ++nt)
          for (int rg = 0; rg < 4; ++rg) {
            const int prow = quad * 4 + rg;
            const int pcol = nt * 16 + r;
            p_lds[wave][prow * 64 + (((pcol >> 3) ^ (prow & 7)) * 8) + (pcol & 7)] =
                (bf16)sa[nt][rg];
          }
        __builtin_amdgcn_s_setprio(1);
        for (int ks2 = 0; ks2 < 2; ++ks2) {
          const int prow = r;
          const bf16x8 pf = *(const bf16x8*)(p_lds[wave] + prow * 64 + (((ks2 * 4 + quad) ^ (prow & 7)) * 8));
          for (int nt2 = 0; nt2 < 8; ++nt2) {
            const int vrow = nt2 * 16 + r;
            const bf16x8 vf = *(const bf16x8*)(&v_lds[cur][0] + vrow * 64 + (((ks2 * 4 + quad) ^ (vrow & 7)) * 8));
            o_acc[nt2] = __builtin_amdgcn_mfma_f32_16x16x32_bf16(pf, vf, o_acc[nt2], 0, 0, 0);
          }
        }
        __builtin_amdgcn_s_setprio(0);
      }
      __syncthreads();
    }

    f32x4 inv;
    for (int rg = 0; rg < 4; ++rg) inv[rg] = 1.0f / l_run[rg];
    for (int nt2 = 0; nt2 < 8; ++nt2) {
      const int d = nt2 * 16 + r;
      for (int rg = 0; rg < 4; ++rg) {
        const int s = qrow0 + quad * 4 + rg;
        Qh[(size_t)s * 128 + d] = (bf16)(o_acc[nt2][rg] * inv[rg]);
      }
    }
  }
}

extern "C" void kernel_launch(void* const* d_in, const int* in_sizes, int n_in,
                              void* d_out, int out_size, void* d_ws, size_t ws_size,
                              hipStream_t stream) {
  const float* x     = (const float*)d_in[0];   // [2,2048,2048] fp32
  const float* Wqkv  = (const float*)d_in[1];   // [6144,2048] fp32
  const float* Wproj = (const float*)d_in[2];   // [2048,2048] fp32
  float* out = (float*)d_out;                   // [2,2048,2048] fp32 = 32 MiB

  const int Bm = 4096, E = 2048;
  const size_t plane = 8388608;                 // 16 MiB as bf16

  // ws (48 MiB): [0,plane) Q plane; [plane,2p) V^T plane; [2p,3p) xb then Wproj_bf16.
  // d_out (32 MiB): [0,plane) bf16 K plane; [plane,+4194304) bf16 Wqkv chunk
  //   (8 MiB, reused 3x); both dead before proj GEMM overwrites d_out.
  bf16* qw  = (bf16*)d_ws;
  bf16* vtw = qw + plane;
  bf16* xb  = vtw + plane;       // later reused for Wproj bf16
  bf16* kw  = (bf16*)d_out;
  bf16* wqb = kw + plane;        // 2048 rows x 2048 = 8 MiB, fits d_out upper half

  // 1) x -> bf16
  conv_f32_bf16<<<8388608 / 2048, 256, 0, stream>>>(x, xb);
  // 2) QKV GEMM in 3 chunks of N=2048 -> each grid 8x32 = 256 blocks = 1/CU
  //    chunk 0: all Q; chunk 1: all K; chunk 2: all V (transposed scatter)
  for (int chunk = 0; chunk < 3; ++chunk) {
    conv_f32_bf16<<<4194304 / 2048, 256, 0, stream>>>(Wqkv + (size_t)chunk * 4194304, wqb);
    gemm_bt2<0, 1><<<dim3(2048 / 256, Bm / 128), 512, 0, stream>>>(
        xb, wqb, nullptr, qw, kw, vtw, Bm, 2048, E, chunk * 2048);
  }
  // 3) attention (O overwrites Q plane); paired causal blocks, 8 waves/block
  attn_kernel<<<dim3(8, 32), 512, 0, stream>>>(qw, kw, vtw, 2048);
  // 4) Wproj -> bf16 (xb region; xb dead)
  conv_f32_bf16<<<4194304 / 2048, 256, 0, stream>>>(Wproj, xb);
  // 5) proj GEMM: A = O plane (gather), C = d_out fp32; grid 8x32 = 256 blocks
  gemm_bt2<2, 0><<<dim3(2048 / 256, Bm / 128), 512, 0, stream>>>(
      qw, xb, out, nullptr, nullptr, nullptr, Bm, 2048, E, 0);
}

// Round 5
// 403.439 us; speedup vs baseline: 1.1159x; 1.0250x over previous
//
#include <hip/hip_runtime.h>
#include <cstdint>
#include <cstddef>

typedef __bf16 bf16;
typedef __bf16 bf16x8 __attribute__((ext_vector_type(8)));
typedef float  f32x4  __attribute__((ext_vector_type(4)));

static_assert(sizeof(bf16x8) == 16, "bf16x8 must be 16B");

// async global->LDS, 16B per lane; lane i's data lands at ldsbase + i*16.
__device__ __forceinline__ void async_copy16(const bf16* g, bf16* l) {
  __builtin_amdgcn_global_load_lds(
      (__attribute__((address_space(1))) void*)(g),
      (__attribute__((address_space(3))) void*)(l),
      16, 0, 0);
}

__device__ __forceinline__ uint32_t lds_u32(const bf16* p) {
  return (uint32_t)(uintptr_t)((__attribute__((address_space(3))) const bf16*)p);
}

// fp32 -> bf16 bulk convert, 8 elems/thread. n must be a multiple of 2048.
__global__ __launch_bounds__(256)
void conv_f32_bf16(const float* __restrict__ s, bf16* __restrict__ d) {
  const size_t i = ((size_t)blockIdx.x * 256 + threadIdx.x) * 8;
  const f32x4 a = *(const f32x4*)(s + i);
  const f32x4 b = *(const f32x4*)(s + i + 4);
  bf16x8 o;
#pragma unroll
  for (int e = 0; e < 4; ++e) { o[e] = (bf16)a[e]; o[4 + e] = (bf16)b[e]; }
  *(bf16x8*)(d + i) = o;
}

// ---------------------------------------------------------------------------
// 128(M) x 256(N) 2-phase-per-K-tile GEMM (unchanged from R4). BK=64,
// 512 threads (8 waves 2Mx4N, wave tile 64x64). C[m,n] = sum_k A[m,k]*W[n,k].
// ---------------------------------------------------------------------------
template<int AMODE>
__device__ __forceinline__ void stageA(const bf16* __restrict__ P, int K,
                                       int row0, int k0, int ks,
                                       bf16* lds, int wave, int lane) {
  const int lin0 = wave * 64;           // wave-uniform
  const int lin  = lin0 + lane;
  const int row  = lin >> 2;            // 0..127
  const int ch   = lin & 3;
  const int gch  = ch ^ ((row >> 1) & 3);
  const bf16* src;
  if constexpr (AMODE == 2) {
    const int rowA = row0 + row;
    const int b = rowA >> 11, s = rowA & 2047;
    const int kk = k0 + ks * 32;
    src = P + ((size_t)(b * 16 + (kk >> 7)) * 2048 + s) * 128 + (kk & 127) + gch * 8;
  } else {
    src = P + (size_t)(row0 + row) * K + k0 + ks * 32 + gch * 8;
  }
  async_copy16(src, lds + ks * 4096 + lin0 * 8);
}

__device__ __forceinline__ void stageW(const bf16* __restrict__ P, int K,
                                       int row0, int k0, int ks,
                                       bf16* lds, int wave, int lane) {
#pragma unroll
  for (int i = 0; i < 2; ++i) {
    const int lin0 = i * 512 + wave * 64;
    const int lin  = lin0 + lane;
    const int row  = lin >> 2;          // 0..255
    const int ch   = lin & 3;
    const int gch  = ch ^ ((row >> 1) & 3);
    async_copy16(P + (size_t)(row0 + row) * K + k0 + ks * 32 + gch * 8,
                 lds + ks * 8192 + lin0 * 8);
  }
}

__device__ __forceinline__ void ld_frags(uint32_t ab, uint32_t bb,
                                         bf16x8 (&a)[4], bf16x8 (&b)[4]) {
  asm volatile("ds_read_b128 %0, %1 offset:0"    : "=v"(a[0]) : "v"(ab));
  asm volatile("ds_read_b128 %0, %1 offset:1024" : "=v"(a[1]) : "v"(ab));
  asm volatile("ds_read_b128 %0, %1 offset:2048" : "=v"(a[2]) : "v"(ab));
  asm volatile("ds_read_b128 %0, %1 offset:3072" : "=v"(a[3]) : "v"(ab));
  asm volatile("ds_read_b128 %0, %1 offset:0"    : "=v"(b[0]) : "v"(bb));
  asm volatile("ds_read_b128 %0, %1 offset:1024" : "=v"(b[1]) : "v"(bb));
  asm volatile("ds_read_b128 %0, %1 offset:2048" : "=v"(b[2]) : "v"(bb));
  asm volatile("ds_read_b128 %0, %1 offset:3072" : "=v"(b[3]) : "v"(bb));
}

// AMODE 0: A row-major [M,K].  AMODE 2: A gathered from [B,H,S,D] plane.
// CMODE 0: C fp32 row-major -> Crow.
// CMODE 1: C scattered bf16; global col = nbase+n: <2048 -> Cq[b,h,s,d],
//          <4096 -> Ck[b,h,s,d], else -> Cvt TRANSPOSED [b,h,d,s].
template<int AMODE, int CMODE>
__global__ __launch_bounds__(512, 2)
void gemm_bt2(const bf16* __restrict__ A, const bf16* __restrict__ W,
              float* __restrict__ Crow, bf16* __restrict__ Cq,
              bf16* __restrict__ Ck, bf16* __restrict__ Cvt,
              int M, int N, int K, int nbase) {
  __shared__ bf16 As[2][2][128 * 32];
  __shared__ bf16 Ws[2][2][256 * 32];

  const int tid  = threadIdx.x;
  const int wave = tid >> 6, lane = tid & 63;
  const int quad = lane >> 4, r = lane & 15;
  const int wr = wave >> 2, wc = wave & 3;   // 2M x 4N wave grid

  // XCD-aware bijective swizzle (nwg = 256 for all our launches, %8==0)
  const int gx  = gridDim.x;
  const int nwg = gx * gridDim.y;
  int wg = blockIdx.y * gx + blockIdx.x;
  wg = (wg & 7) * (nwg >> 3) + (wg >> 3);
  const int m0 = (wg / gx) * 128;
  const int n0 = (wg % gx) * 256;

  const int wm = wr * 64, wn = wc * 64;
  const int nT = K >> 6;
  const int cs = quad ^ ((r >> 1) & 3);      // read chunk (A and W)

  f32x4 acc[4][4] = {};

  const uint32_t a_rd = lds_u32(&As[0][0][0]) + (((wm + r) * 32 + cs * 8) << 1);
  const uint32_t b_rd = lds_u32(&Ws[0][0][0]) + (((wn + r) * 32 + cs * 8) << 1);

  // prologue: Kh0(0), Kh1(0), Kh0(1)
  stageA<AMODE>(A, K, m0, 0, 0, &As[0][0][0], wave, lane);
  stageW(W, K, n0, 0, 0, &Ws[0][0][0], wave, lane);
  stageA<AMODE>(A, K, m0, 0, 1, &As[0][0][0], wave, lane);
  stageW(W, K, n0, 0, 1, &Ws[0][0][0], wave, lane);
  if (nT > 1) {
    stageA<AMODE>(A, K, m0, 64, 0, &As[1][0][0], wave, lane);
    stageW(W, K, n0, 64, 0, &Ws[1][0][0], wave, lane);
    asm volatile("s_waitcnt vmcnt(6)" ::: "memory");   // Kh0(0) resident
  } else {
    asm volatile("s_waitcnt vmcnt(3)" ::: "memory");
  }
  __builtin_amdgcn_s_barrier();

  for (int t = 0; t < nT; ++t) {
    const int c = t & 1;
    bf16x8 af[4], bw[4];

    // ---- phase ks=0: reads buf c ks0; stages Kh1(t+1) -> buf^1 ----
    ld_frags(a_rd + (c * 2 + 0) * 8192, b_rd + (c * 2 + 0) * 16384, af, bw);
    if (t + 1 < nT) {
      stageA<AMODE>(A, K, m0, (t + 1) << 6, 1, &As[c ^ 1][0][0], wave, lane);
      stageW(W, K, n0, (t + 1) << 6, 1, &Ws[c ^ 1][0][0], wave, lane);
      asm volatile("s_waitcnt vmcnt(6)" ::: "memory");  // Kh1(t) resident
    } else {
      asm volatile("s_waitcnt vmcnt(0)" ::: "memory");
    }
    __builtin_amdgcn_sched_barrier(0);
    __builtin_amdgcn_s_barrier();
    asm volatile("s_waitcnt lgkmcnt(0)" ::: "memory");
    __builtin_amdgcn_sched_barrier(0);
    __builtin_amdgcn_s_setprio(1);
#pragma unroll
    for (int m = 0; m < 4; ++m)
#pragma unroll
      for (int n = 0; n < 4; ++n)
        acc[m][n] = __builtin_amdgcn_mfma_f32_16x16x32_bf16(af[m], bw[n], acc[m][n], 0, 0, 0);
    __builtin_amdgcn_s_setprio(0);
    __builtin_amdgcn_s_barrier();

    // ---- phase ks=1: reads buf c ks1; stages Kh0(t+2) -> buf c ----
    ld_frags(a_rd + (c * 2 + 1) * 8192, b_rd + (c * 2 + 1) * 16384, af, bw);
    if (t + 2 < nT) {
      stageA<AMODE>(A, K, m0, (t + 2) << 6, 0, &As[c][0][0], wave, lane);
      stageW(W, K, n0, (t + 2) << 6, 0, &Ws[c][0][0], wave, lane);
      asm volatile("s_waitcnt vmcnt(6)" ::: "memory");  // Kh0(t+1) resident
    } else if (t + 1 < nT) {
      asm volatile("s_waitcnt vmcnt(3)" ::: "memory");
    } else {
      asm volatile("s_waitcnt vmcnt(0)" ::: "memory");
    }
    __builtin_amdgcn_sched_barrier(0);
    __builtin_amdgcn_s_barrier();
    asm volatile("s_waitcnt lgkmcnt(0)" ::: "memory");
    __builtin_amdgcn_sched_barrier(0);
    __builtin_amdgcn_s_setprio(1);
#pragma unroll
    for (int m = 0; m < 4; ++m)
#pragma unroll
      for (int n = 0; n < 4; ++n)
        acc[m][n] = __builtin_amdgcn_mfma_f32_16x16x32_bf16(af[m], bw[n], acc[m][n], 0, 0, 0);
    __builtin_amdgcn_s_setprio(0);
    __builtin_amdgcn_s_barrier();
  }

  // C-layout: row = quad*4+reg, col = lane&15 (m89-verified).
#pragma unroll
  for (int i = 0; i < 4; ++i) {
    const int growb = m0 + wm + i * 16 + quad * 4;
#pragma unroll
    for (int j = 0; j < 4; ++j) {
      const int gcol = n0 + wn + j * 16 + r;
#pragma unroll
      for (int rg = 0; rg < 4; ++rg) {
        const int grow = growb + rg;
        if constexpr (CMODE == 1) {
          const int gc = nbase + gcol;
          const int which = gc >> 11;
          const int h = (gc >> 7) & 15;
          const int d = gc & 127;
          const int b = grow >> 11;
          const int s = grow & 2047;
          const bf16 v = (bf16)acc[i][j][rg];
          if (which == 0)
            Cq[(((size_t)b * 16 + h) * 2048 + s) * 128 + d] = v;
          else if (which == 1)
            Ck[(((size_t)b * 16 + h) * 2048 + s) * 128 + d] = v;
          else
            Cvt[(((size_t)b * 16 + h) * 128 + d) * 2048 + s] = v;  // transposed
        } else {
          Crow[(size_t)grow * N + gcol] = acc[i][j][rg];
        }
      }
    }
  }
}

// Flash attention, causal. Q,K: [B*H, S, 128] bf16; Vt: [B*H, 128, S] bf16
// (pre-transposed). O written IN-PLACE into the Q plane (block-private rows).
//
// R5 restructure for block-level TLP: QBLK=64, 4 waves (256 thr), grid
// (16, B*H) = 512 blocks = exactly 2 blocks/CU (LDS 72KB). The two blocks
// on a CU have INDEPENDENT barriers: when one stalls at vmcnt/softmax, the
// other's waves feed the MFMA pipe (R2..R4 showed the single-block barrier
// locks all 8 waves together -> MfmaUtil stuck at 12.5%).
// Causal pairing: block i does 64-row q-tiles {31-i, i} -> uniform 33
// KV-tiles/block. No wave is ever fully masked (kv0 <= q0 <= qrow0 always).
// Staging: double-buffered global_load_lds, 8 instrs/thread/tile, counted
// vmcnt(8) so next tile stays in flight (T3+T4). T5 setprio, T13 defer-max.
__global__ __launch_bounds__(256, 2)
void attn_kernel(bf16* __restrict__ Q, const bf16* __restrict__ K,
                 const bf16* __restrict__ Vt, int S) {
  __shared__ bf16 k_lds[2][64 * 128];   // [kv][d], swizzled   32 KB
  __shared__ bf16 v_lds[2][128 * 64];   // [d][kv], swizzled   32 KB
  __shared__ bf16 p_lds[4][16 * 64];    // per-wave P           8 KB

  const int tid = threadIdx.x, wave = tid >> 6, lane = tid & 63;
  const int quad = lane >> 4, r = lane & 15;
  const int bh = blockIdx.y;
  bf16* Qh = Q + (size_t)bh * S * 128;
  const bf16* Kh = K + (size_t)bh * S * 128;
  const bf16* Vth = Vt + (size_t)bh * 128 * S;

  const float sc = 0.0883883476483184f * 1.4426950408889634f; // 1/sqrt(128)*log2e

  // One KV tile = K 16KB + V 16KB = 8 async 16B instrs/thread (256 thr).
  // LDS dest linear (wave-uniform base); XOR chunk swizzle on GLOBAL source.
  auto issue_stage = [&](int kv0, int buf) {
#pragma unroll
    for (int j = 0; j < 4; ++j) {
      const int lin0 = j * 256 + wave * 64;       // wave-uniform
      const int lin = lin0 + lane;
      const int row = lin >> 4, ch = lin & 15;    // K: [64 kv][16 chunks]
      async_copy16(Kh + (size_t)(kv0 + row) * 128 + ((ch ^ (row & 7)) << 3),
                   &k_lds[buf][0] + lin0 * 8);
    }
#pragma unroll
    for (int j = 0; j < 4; ++j) {
      const int lin0 = j * 256 + wave * 64;
      const int lin = lin0 + lane;
      const int row = lin >> 3, c = lin & 7;      // V^T: [128 d][8 chunks]
      async_copy16(Vth + (size_t)row * S + kv0 + ((c ^ (row & 7)) << 3),
                   &v_lds[buf][0] + lin0 * 8);
    }
  };

  for (int pass = 0; pass < 2; ++pass) {
    const int qb = pass ? blockIdx.x : (31 - blockIdx.x);  // heavy tile first
    const int q0 = qb << 6;
    const int qrow0 = q0 + wave * 16;   // 16 q-rows per wave, 4 waves = 64
    const int nkv = qb + 1;

    // Q fragments in registers: A[m=lane&15][k=quad*8+j] per 32-k step
    bf16x8 qf[4];
    for (int ks = 0; ks < 4; ++ks)
      qf[ks] = *(const bf16x8*)(Qh + (size_t)(qrow0 + r) * 128 + ks * 32 + quad * 8);

    f32x4 o_acc[8] = {};
    f32x4 m_run, l_run;
    for (int t = 0; t < 4; ++t) { m_run[t] = -1e30f; l_run[t] = 0.f; }

    issue_stage(0, 0);  // prologue (prev pass fully drained by its tail)

    for (int kt = 0; kt < nkv; ++kt) {
      const int kv0 = kt << 6;
      const int cur = kt & 1;
      if (kt + 1 < nkv) {
        issue_stage((kt + 1) << 6, cur ^ 1);
        asm volatile("s_waitcnt vmcnt(8)" ::: "memory");  // cur tile resident
      } else {
        asm volatile("s_waitcnt vmcnt(0)" ::: "memory");
      }
      __builtin_amdgcn_sched_barrier(0);
      __syncthreads();

      {
        // S = Q K^T
        f32x4 sa[4] = {};
        __builtin_amdgcn_s_setprio(1);
        for (int ks = 0; ks < 4; ++ks) {
          bf16x8 kf[4];
          for (int nt = 0; nt < 4; ++nt) {
            const int kr = nt * 16 + r;
            kf[nt] = *(const bf16x8*)(&k_lds[cur][0] + kr * 128 + (((ks * 4 + quad) ^ (kr & 7)) << 3));
          }
          for (int nt = 0; nt < 4; ++nt)
            sa[nt] = __builtin_amdgcn_mfma_f32_16x16x32_bf16(qf[ks], kf[nt], sa[nt], 0, 0, 0);
        }
        __builtin_amdgcn_s_setprio(0);
        // causal mask on diagonal tiles
        if (kv0 + 63 > qrow0) {
          for (int nt = 0; nt < 4; ++nt) {
            const int col  = kv0 + nt * 16 + r;
            const int rowb = qrow0 + quad * 4;
            for (int rg = 0; rg < 4; ++rg)
              if (col > rowb + rg) sa[nt][rg] = -1e30f;
          }
        }
        // online softmax (each score row lives on the 16 lanes of one quad)
        f32x4 mx = sa[0];
        for (int nt = 1; nt < 4; ++nt)
          for (int rg = 0; rg < 4; ++rg) mx[rg] = fmaxf(mx[rg], sa[nt][rg]);
        for (int off = 1; off < 16; off <<= 1)
          for (int rg = 0; rg < 4; ++rg) mx[rg] = fmaxf(mx[rg], __shfl_xor(mx[rg], off, 64));
        // T13 defer-max: rescale only when growth is material (P <= 2^8).
        float need = mx[0] - m_run[0];
        for (int rg = 1; rg < 4; ++rg) need = fmaxf(need, mx[rg] - m_run[rg]);
        if (need * sc > 8.0f) {
          f32x4 alpha;
          for (int rg = 0; rg < 4; ++rg) {
            const float mnew = fmaxf(m_run[rg], mx[rg]);
            alpha[rg] = exp2f((m_run[rg] - mnew) * sc);
            m_run[rg] = mnew;
            l_run[rg] *= alpha[rg];
          }
          for (int nt2 = 0; nt2 < 8; ++nt2)
            for (int rg = 0; rg < 4; ++rg) o_acc[nt2][rg] *= alpha[rg];
        }
        f32x4 rsum = {0.f, 0.f, 0.f, 0.f};
        for (int nt = 0; nt < 4; ++nt)
          for (int rg = 0; rg < 4; ++rg) {
            const float p = exp2f((sa[nt][rg] - m_run[rg]) * sc);
            sa[nt][rg] = p;
            rsum[rg] += p;
          }
        for (int off = 1; off < 16; off <<= 1)
          for (int rg = 0; rg < 4; ++rg) rsum[rg] += __shfl_xor(rsum[rg], off, 64);
        for (int rg = 0; rg < 4; ++rg) l_run[rg] += rsum[rg];
        // P: C-layout -> A-layout via per-wave LDS round-trip, swizzled
        for (int nt = 0; nt < 4; ++nt)
          for (int rg = 0; rg < 4; ++rg) {
            const int prow = quad * 4 + rg;
            const int pcol = nt * 16 + r;
            p_lds[wave][prow * 64 + (((pcol >> 3) ^ (prow & 7)) * 8) + (pcol & 7)] =
                (bf16)sa[nt][rg];
          }
        // O += P V
        __builtin_amdgcn_s_setprio(1);
        for (int ks2 = 0; ks2 < 2; ++ks2) {
          const int prow = r;
          const bf16x8 pf = *(const bf16x8*)(p_lds[wave] + prow * 64 + (((ks2 * 4 + quad) ^ (prow & 7)) * 8));
          for (int nt2 = 0; nt2 < 8; ++nt2) {
            const int vrow = nt2 * 16 + r;
            const bf16x8 vf = *(const bf16x8*)(&v_lds[cur][0] + vrow * 64 + (((ks2 * 4 + quad) ^ (vrow & 7)) * 8));
            o_acc[nt2] = __builtin_amdgcn_mfma_f32_16x16x32_bf16(pf, vf, o_acc[nt2], 0, 0, 0);
          }
        }
        __builtin_amdgcn_s_setprio(0);
      }
      __syncthreads();
    }

    // epilogue: write O back into the Q plane, same [b,h,s,d] coords
    f32x4 inv;
    for (int rg = 0; rg < 4; ++rg) inv[rg] = 1.0f / l_run[rg];
    for (int nt2 = 0; nt2 < 8; ++nt2) {
      const int d = nt2 * 16 + r;
      for (int rg = 0; rg < 4; ++rg) {
        const int s = qrow0 + quad * 4 + rg;
        Qh[(size_t)s * 128 + d] = (bf16)(o_acc[nt2][rg] * inv[rg]);
      }
    }
  }
}

extern "C" void kernel_launch(void* const* d_in, const int* in_sizes, int n_in,
                              void* d_out, int out_size, void* d_ws, size_t ws_size,
                              hipStream_t stream) {
  const float* x     = (const float*)d_in[0];   // [2,2048,2048] fp32
  const float* Wqkv  = (const float*)d_in[1];   // [6144,2048] fp32
  const float* Wproj = (const float*)d_in[2];   // [2048,2048] fp32
  float* out = (float*)d_out;                   // [2,2048,2048] fp32 = 32 MiB

  const int Bm = 4096, E = 2048;
  const size_t plane = 8388608;                 // 16 MiB as bf16

  // ws (48 MiB): [0,plane) Q plane; [plane,2p) V^T plane; [2p,3p) xb then Wproj_bf16.
  // d_out (32 MiB): [0,plane) bf16 K plane; [plane,+4194304) bf16 Wqkv chunk
  //   (8 MiB, reused 3x); both dead before proj GEMM overwrites d_out.
  bf16* qw  = (bf16*)d_ws;
  bf16* vtw = qw + plane;
  bf16* xb  = vtw + plane;       // later reused for Wproj bf16
  bf16* kw  = (bf16*)d_out;
  bf16* wqb = kw + plane;        // 2048 rows x 2048 = 8 MiB, fits d_out upper half

  // 1) x -> bf16
  conv_f32_bf16<<<8388608 / 2048, 256, 0, stream>>>(x, xb);
  // 2) QKV GEMM in 3 chunks of N=2048 -> each grid 8x32 = 256 blocks = 1/CU
  //    chunk 0: all Q; chunk 1: all K; chunk 2: all V (transposed scatter)
  for (int chunk = 0; chunk < 3; ++chunk) {
    conv_f32_bf16<<<4194304 / 2048, 256, 0, stream>>>(Wqkv + (size_t)chunk * 4194304, wqb);
    gemm_bt2<0, 1><<<dim3(2048 / 256, Bm / 128), 512, 0, stream>>>(
        xb, wqb, nullptr, qw, kw, vtw, Bm, 2048, E, chunk * 2048);
  }
  // 3) attention (O overwrites Q plane); paired causal 64-row tiles,
  //    512 blocks = 2 independent blocks/CU for TLP
  attn_kernel<<<dim3(16, 32), 256, 0, stream>>>(qw, kw, vtw, 2048);
  // 4) Wproj -> bf16 (xb region; xb dead)
  conv_f32_bf16<<<4194304 / 2048, 256, 0, stream>>>(Wproj, xb);
  // 5) proj GEMM: A = O plane (gather), C = d_out fp32; grid 8x32 = 256 blocks
  gemm_bt2<2, 0><<<dim3(2048 / 256, Bm / 128), 512, 0, stream>>>(
      qw, xb, out, nullptr, nullptr, nullptr, Bm, 2048, E, 0);
}

// Round 6
// 400.905 us; speedup vs baseline: 1.1230x; 1.0063x over previous
//
#include <hip/hip_runtime.h>
#include <cstdint>
#include <cstddef>

typedef __bf16 bf16;
typedef __bf16 bf16x8 __attribute__((ext_vector_type(8)));
typedef float  f32x4  __attribute__((ext_vector_type(4)));

static_assert(sizeof(bf16x8) == 16, "bf16x8 must be 16B");

// async global->LDS, 16B per lane; lane i's data lands at ldsbase + i*16.
__device__ __forceinline__ void async_copy16(const bf16* g, bf16* l) {
  __builtin_amdgcn_global_load_lds(
      (__attribute__((address_space(1))) void*)(g),
      (__attribute__((address_space(3))) void*)(l),
      16, 0, 0);
}

__device__ __forceinline__ uint32_t lds_u32(const bf16* p) {
  return (uint32_t)(uintptr_t)((__attribute__((address_space(3))) const bf16*)p);
}

// fp32 -> bf16 bulk convert, 8 elems/thread. n must be a multiple of 2048.
__global__ __launch_bounds__(256)
void conv_f32_bf16(const float* __restrict__ s, bf16* __restrict__ d) {
  const size_t i = ((size_t)blockIdx.x * 256 + threadIdx.x) * 8;
  const f32x4 a = *(const f32x4*)(s + i);
  const f32x4 b = *(const f32x4*)(s + i + 4);
  bf16x8 o;
#pragma unroll
  for (int e = 0; e < 4; ++e) { o[e] = (bf16)a[e]; o[4 + e] = (bf16)b[e]; }
  *(bf16x8*)(d + i) = o;
}

// ---------------------------------------------------------------------------
// 128(M) x 256(N) GEMM, BK=32, 5-deep rotating prefetch (R6).
// 512 threads (8 waves 2Mx4N, wave tile 64x64). C[m,n] = sum_k A[m,k]*W[n,k].
// LDS: As[5][128*32] (40KB) + Ws[5][256*32] (80KB) = 120KB, 1 block/CU.
// Phase t (one K-tile, 16 MFMA/wave):
//   ds_read tile t (buf t%5)            -- tile t guaranteed by phase t-1
//   stage tile t+4 -> buf (t+4)%5       -- == buf (t-1)%5, reads done & published
//   vmcnt(9)                            -- allows tiles t+2..t+4 (9 instrs) in
//                                          flight; forces tile t+1 landed.
//                                          t+1 was ISSUED 4 phases ago => >1000cy
//                                          flight (R3/R4 bug: only ~2 phases).
//   lgkmcnt(0) + sched_barrier (rule 18); setprio(1); 16 MFMA; setprio(0)
//   s_barrier                           -- publishes vmcnt guarantee (tile t+1
//                                          readable next phase) AND my reads-
//                                          complete (buf t%5 restageable next
//                                          phase). All waits precede it.
// Tail: vmcnt 9 -> 6 -> 3 -> 0 as staging runs out.
// Swizzle (rule #21): LDS[row][ch] = G[row][ch ^ ((row>>1)&3)], applied to the
// GLOBAL source; read chunk cs = quad ^ ((r>>1)&3) -> uniform 8 words/bank.
// ---------------------------------------------------------------------------
template<int AMODE>
__device__ __forceinline__ void stageA32(const bf16* __restrict__ P, int K,
                                         int row0, int k0,
                                         bf16* lds, int wave, int lane) {
  const int lin0 = wave * 64;           // wave-uniform
  const int lin  = lin0 + lane;
  const int row  = lin >> 2;            // 0..127
  const int ch   = lin & 3;
  const int gch  = ch ^ ((row >> 1) & 3);
  const bf16* src;
  if constexpr (AMODE == 2) {
    const int rowA = row0 + row;
    const int b = rowA >> 11, s = rowA & 2047;
    src = P + ((size_t)(b * 16 + (k0 >> 7)) * 2048 + s) * 128 + (k0 & 127) + gch * 8;
  } else {
    src = P + (size_t)(row0 + row) * K + k0 + gch * 8;
  }
  async_copy16(src, lds + lin0 * 8);
}

__device__ __forceinline__ void stageW32(const bf16* __restrict__ P, int K,
                                         int row0, int k0,
                                         bf16* lds, int wave, int lane) {
#pragma unroll
  for (int i = 0; i < 2; ++i) {
    const int lin0 = i * 512 + wave * 64;
    const int lin  = lin0 + lane;
    const int row  = lin >> 2;          // 0..255
    const int ch   = lin & 3;
    const int gch  = ch ^ ((row >> 1) & 3);
    async_copy16(P + (size_t)(row0 + row) * K + k0 + gch * 8,
                 lds + lin0 * 8);
  }
}

__device__ __forceinline__ void ld_frags(uint32_t ab, uint32_t bb,
                                         bf16x8 (&a)[4], bf16x8 (&b)[4]) {
  asm volatile("ds_read_b128 %0, %1 offset:0"    : "=v"(a[0]) : "v"(ab));
  asm volatile("ds_read_b128 %0, %1 offset:1024" : "=v"(a[1]) : "v"(ab));
  asm volatile("ds_read_b128 %0, %1 offset:2048" : "=v"(a[2]) : "v"(ab));
  asm volatile("ds_read_b128 %0, %1 offset:3072" : "=v"(a[3]) : "v"(ab));
  asm volatile("ds_read_b128 %0, %1 offset:0"    : "=v"(b[0]) : "v"(bb));
  asm volatile("ds_read_b128 %0, %1 offset:1024" : "=v"(b[1]) : "v"(bb));
  asm volatile("ds_read_b128 %0, %1 offset:2048" : "=v"(b[2]) : "v"(bb));
  asm volatile("ds_read_b128 %0, %1 offset:3072" : "=v"(b[3]) : "v"(bb));
}

// AMODE 0: A row-major [M,K].  AMODE 2: A gathered from [B,H,S,D] plane.
// CMODE 0: C fp32 row-major -> Crow.
// CMODE 1: C scattered bf16; global col = nbase+n: <2048 -> Cq[b,h,s,d],
//          <4096 -> Ck[b,h,s,d], else -> Cvt TRANSPOSED [b,h,d,s].
template<int AMODE, int CMODE>
__global__ __launch_bounds__(512, 2)
void gemm_bt3(const bf16* __restrict__ A, const bf16* __restrict__ W,
              float* __restrict__ Crow, bf16* __restrict__ Cq,
              bf16* __restrict__ Ck, bf16* __restrict__ Cvt,
              int M, int N, int K, int nbase) {
  __shared__ bf16 As[5][128 * 32];
  __shared__ bf16 Ws[5][256 * 32];

  const int tid  = threadIdx.x;
  const int wave = tid >> 6, lane = tid & 63;
  const int quad = lane >> 4, r = lane & 15;
  const int wr = wave >> 2, wc = wave & 3;   // 2M x 4N wave grid

  // XCD-aware bijective swizzle (nwg = 256 for all our launches, %8==0)
  const int gx  = gridDim.x;
  const int nwg = gx * gridDim.y;
  int wg = blockIdx.y * gx + blockIdx.x;
  wg = (wg & 7) * (nwg >> 3) + (wg >> 3);
  const int m0 = (wg / gx) * 128;
  const int n0 = (wg % gx) * 256;

  const int wm = wr * 64, wn = wc * 64;
  const int nT = K >> 5;
  const int cs = quad ^ ((r >> 1) & 3);      // read chunk (A and W)

  f32x4 acc[4][4] = {};

  const uint32_t a_rd = lds_u32(&As[0][0]) + (((wm + r) * 32 + cs * 8) << 1);
  const uint32_t b_rd = lds_u32(&Ws[0][0]) + (((wn + r) * 32 + cs * 8) << 1);

  // prologue: stage tiles 0..3 (12 load-instrs)
#pragma unroll
  for (int i = 0; i < 4; ++i)
    if (i < nT) {
      stageA32<AMODE>(A, K, m0, i << 5, &As[i][0], wave, lane);
      stageW32(W, K, n0, i << 5, &Ws[i][0], wave, lane);
    }
  if (nT > 3)       asm volatile("s_waitcnt vmcnt(9)" ::: "memory");
  else if (nT == 3) asm volatile("s_waitcnt vmcnt(6)" ::: "memory");
  else if (nT == 2) asm volatile("s_waitcnt vmcnt(3)" ::: "memory");
  else              asm volatile("s_waitcnt vmcnt(0)" ::: "memory");
  __builtin_amdgcn_sched_barrier(0);
  __builtin_amdgcn_s_barrier();

  int bc = 0;   // t % 5 (read buf)
  int bs = 4;   // (t+4) % 5 (stage buf)
  for (int t = 0; t < nT; ++t) {
    bf16x8 af[4], bw[4];
    ld_frags(a_rd + bc * 8192, b_rd + bc * 16384, af, bw);
    if (t + 4 < nT) {
      stageA32<AMODE>(A, K, m0, (t + 4) << 5, &As[bs][0], wave, lane);
      stageW32(W, K, n0, (t + 4) << 5, &Ws[bs][0], wave, lane);
      asm volatile("s_waitcnt vmcnt(9)" ::: "memory");   // tile t+1 landed
    } else if (t + 4 == nT) {
      asm volatile("s_waitcnt vmcnt(6)" ::: "memory");
    } else if (t + 3 == nT) {
      asm volatile("s_waitcnt vmcnt(3)" ::: "memory");
    } else {
      asm volatile("s_waitcnt vmcnt(0)" ::: "memory");
    }
    __builtin_amdgcn_sched_barrier(0);
    asm volatile("s_waitcnt lgkmcnt(0)" ::: "memory");
    __builtin_amdgcn_sched_barrier(0);
    __builtin_amdgcn_s_setprio(1);
#pragma unroll
    for (int m = 0; m < 4; ++m)
#pragma unroll
      for (int n = 0; n < 4; ++n)
        acc[m][n] = __builtin_amdgcn_mfma_f32_16x16x32_bf16(af[m], bw[n], acc[m][n], 0, 0, 0);
    __builtin_amdgcn_s_setprio(0);
    __builtin_amdgcn_s_barrier();
    bc = (bc + 1 == 5) ? 0 : bc + 1;
    bs = (bs + 1 == 5) ? 0 : bs + 1;
  }

  // C-layout: row = quad*4+reg, col = lane&15 (m89-verified).
#pragma unroll
  for (int i = 0; i < 4; ++i) {
    const int growb = m0 + wm + i * 16 + quad * 4;
#pragma unroll
    for (int j = 0; j < 4; ++j) {
      const int gcol = n0 + wn + j * 16 + r;
#pragma unroll
      for (int rg = 0; rg < 4; ++rg) {
        const int grow = growb + rg;
        if constexpr (CMODE == 1) {
          const int gc = nbase + gcol;
          const int which = gc >> 11;
          const int h = (gc >> 7) & 15;
          const int d = gc & 127;
          const int b = grow >> 11;
          const int s = grow & 2047;
          const bf16 v = (bf16)acc[i][j][rg];
          if (which == 0)
            Cq[(((size_t)b * 16 + h) * 2048 + s) * 128 + d] = v;
          else if (which == 1)
            Ck[(((size_t)b * 16 + h) * 2048 + s) * 128 + d] = v;
          else
            Cvt[(((size_t)b * 16 + h) * 128 + d) * 2048 + s] = v;  // transposed
        } else {
          Crow[(size_t)grow * N + gcol] = acc[i][j][rg];
        }
      }
    }
  }
}

// Flash attention, causal (unchanged from R5 — control). Q,K: [B*H, S, 128]
// bf16; Vt: [B*H, 128, S] bf16. O written IN-PLACE into the Q plane.
// QBLK=64, 4 waves, grid (16, B*H) = 512 blocks = 2 independent blocks/CU.
__global__ __launch_bounds__(256, 2)
void attn_kernel(bf16* __restrict__ Q, const bf16* __restrict__ K,
                 const bf16* __restrict__ Vt, int S) {
  __shared__ bf16 k_lds[2][64 * 128];   // [kv][d], swizzled   32 KB
  __shared__ bf16 v_lds[2][128 * 64];   // [d][kv], swizzled   32 KB
  __shared__ bf16 p_lds[4][16 * 64];    // per-wave P           8 KB

  const int tid = threadIdx.x, wave = tid >> 6, lane = tid & 63;
  const int quad = lane >> 4, r = lane & 15;
  const int bh = blockIdx.y;
  bf16* Qh = Q + (size_t)bh * S * 128;
  const bf16* Kh = K + (size_t)bh * S * 128;
  const bf16* Vth = Vt + (size_t)bh * 128 * S;

  const float sc = 0.0883883476483184f * 1.4426950408889634f; // 1/sqrt(128)*log2e

  auto issue_stage = [&](int kv0, int buf) {
#pragma unroll
    for (int j = 0; j < 4; ++j) {
      const int lin0 = j * 256 + wave * 64;       // wave-uniform
      const int lin = lin0 + lane;
      const int row = lin >> 4, ch = lin & 15;    // K: [64 kv][16 chunks]
      async_copy16(Kh + (size_t)(kv0 + row) * 128 + ((ch ^ (row & 7)) << 3),
                   &k_lds[buf][0] + lin0 * 8);
    }
#pragma unroll
    for (int j = 0; j < 4; ++j) {
      const int lin0 = j * 256 + wave * 64;
      const int lin = lin0 + lane;
      const int row = lin >> 3, c = lin & 7;      // V^T: [128 d][8 chunks]
      async_copy16(Vth + (size_t)row * S + kv0 + ((c ^ (row & 7)) << 3),
                   &v_lds[buf][0] + lin0 * 8);
    }
  };

  for (int pass = 0; pass < 2; ++pass) {
    const int qb = pass ? blockIdx.x : (31 - blockIdx.x);  // heavy tile first
    const int q0 = qb << 6;
    const int qrow0 = q0 + wave * 16;   // 16 q-rows per wave, 4 waves = 64
    const int nkv = qb + 1;

    bf16x8 qf[4];
    for (int ks = 0; ks < 4; ++ks)
      qf[ks] = *(const bf16x8*)(Qh + (size_t)(qrow0 + r) * 128 + ks * 32 + quad * 8);

    f32x4 o_acc[8] = {};
    f32x4 m_run, l_run;
    for (int t = 0; t < 4; ++t) { m_run[t] = -1e30f; l_run[t] = 0.f; }

    issue_stage(0, 0);  // prologue (prev pass fully drained by its tail)

    for (int kt = 0; kt < nkv; ++kt) {
      const int kv0 = kt << 6;
      const int cur = kt & 1;
      if (kt + 1 < nkv) {
        issue_stage((kt + 1) << 6, cur ^ 1);
        asm volatile("s_waitcnt vmcnt(8)" ::: "memory");  // cur tile resident
      } else {
        asm volatile("s_waitcnt vmcnt(0)" ::: "memory");
      }
      __builtin_amdgcn_sched_barrier(0);
      __syncthreads();

      {
        // S = Q K^T
        f32x4 sa[4] = {};
        __builtin_amdgcn_s_setprio(1);
        for (int ks = 0; ks < 4; ++ks) {
          bf16x8 kf[4];
          for (int nt = 0; nt < 4; ++nt) {
            const int kr = nt * 16 + r;
            kf[nt] = *(const bf16x8*)(&k_lds[cur][0] + kr * 128 + (((ks * 4 + quad) ^ (kr & 7)) << 3));
          }
          for (int nt = 0; nt < 4; ++nt)
            sa[nt] = __builtin_amdgcn_mfma_f32_16x16x32_bf16(qf[ks], kf[nt], sa[nt], 0, 0, 0);
        }
        __builtin_amdgcn_s_setprio(0);
        // causal mask on diagonal tiles
        if (kv0 + 63 > qrow0) {
          for (int nt = 0; nt < 4; ++nt) {
            const int col  = kv0 + nt * 16 + r;
            const int rowb = qrow0 + quad * 4;
            for (int rg = 0; rg < 4; ++rg)
              if (col > rowb + rg) sa[nt][rg] = -1e30f;
          }
        }
        // online softmax (each score row lives on the 16 lanes of one quad)
        f32x4 mx = sa[0];
        for (int nt = 1; nt < 4; ++nt)
          for (int rg = 0; rg < 4; ++rg) mx[rg] = fmaxf(mx[rg], sa[nt][rg]);
        for (int off = 1; off < 16; off <<= 1)
          for (int rg = 0; rg < 4; ++rg) mx[rg] = fmaxf(mx[rg], __shfl_xor(mx[rg], off, 64));
        // T13 defer-max: rescale only when growth is material (P <= 2^8).
        float need = mx[0] - m_run[0];
        for (int rg = 1; rg < 4; ++rg) need = fmaxf(need, mx[rg] - m_run[rg]);
        if (need * sc > 8.0f) {
          f32x4 alpha;
          for (int rg = 0; rg < 4; ++rg) {
            const float mnew = fmaxf(m_run[rg], mx[rg]);
            alpha[rg] = exp2f((m_run[rg] - mnew) * sc);
            m_run[rg] = mnew;
            l_run[rg] *= alpha[rg];
          }
          for (int nt2 = 0; nt2 < 8; ++nt2)
            for (int rg = 0; rg < 4; ++rg) o_acc[nt2][rg] *= alpha[rg];
        }
        f32x4 rsum = {0.f, 0.f, 0.f, 0.f};
        for (int nt = 0; nt < 4; ++nt)
          for (int rg = 0; rg < 4; ++rg) {
            const float p = exp2f((sa[nt][rg] - m_run[rg]) * sc);
            sa[nt][rg] = p;
            rsum[rg] += p;
          }
        for (int off = 1; off < 16; off <<= 1)
          for (int rg = 0; rg < 4; ++rg) rsum[rg] += __shfl_xor(rsum[rg], off, 64);
        for (int rg = 0; rg < 4; ++rg) l_run[rg] += rsum[rg];
        // P: C-layout -> A-layout via per-wave LDS round-trip, swizzled
        for (int nt = 0; nt < 4; ++nt)
          for (int rg = 0; rg < 4; ++rg) {
            const int prow = quad * 4 + rg;
            const int pcol = nt * 16 + r;
            p_lds[wave][prow * 64 + (((pcol >> 3) ^ (prow & 7)) * 8) + (pcol & 7)] =
                (bf16)sa[nt][rg];
          }
        // O += P V
        __builtin_amdgcn_s_setprio(1);
        for (int ks2 = 0; ks2 < 2; ++ks2) {
          const int prow = r;
          const bf16x8 pf = *(const bf16x8*)(p_lds[wave] + prow * 64 + (((ks2 * 4 + quad) ^ (prow & 7)) * 8));
          for (int nt2 = 0; nt2 < 8; ++nt2) {
            const int vrow = nt2 * 16 + r;
            const bf16x8 vf = *(const bf16x8*)(&v_lds[cur][0] + vrow * 64 + (((ks2 * 4 + quad) ^ (vrow & 7)) * 8));
            o_acc[nt2] = __builtin_amdgcn_mfma_f32_16x16x32_bf16(pf, vf, o_acc[nt2], 0, 0, 0);
          }
        }
        __builtin_amdgcn_s_setprio(0);
      }
      __syncthreads();
    }

    // epilogue: write O back into the Q plane, same [b,h,s,d] coords
    f32x4 inv;
    for (int rg = 0; rg < 4; ++rg) inv[rg] = 1.0f / l_run[rg];
    for (int nt2 = 0; nt2 < 8; ++nt2) {
      const int d = nt2 * 16 + r;
      for (int rg = 0; rg < 4; ++rg) {
        const int s = qrow0 + quad * 4 + rg;
        Qh[(size_t)s * 128 + d] = (bf16)(o_acc[nt2][rg] * inv[rg]);
      }
    }
  }
}

extern "C" void kernel_launch(void* const* d_in, const int* in_sizes, int n_in,
                              void* d_out, int out_size, void* d_ws, size_t ws_size,
                              hipStream_t stream) {
  const float* x     = (const float*)d_in[0];   // [2,2048,2048] fp32
  const float* Wqkv  = (const float*)d_in[1];   // [6144,2048] fp32
  const float* Wproj = (const float*)d_in[2];   // [2048,2048] fp32
  float* out = (float*)d_out;                   // [2,2048,2048] fp32 = 32 MiB

  const int Bm = 4096, E = 2048;
  const size_t plane = 8388608;                 // 16 MiB as bf16

  // ws (48 MiB): [0,plane) Q plane; [plane,2p) V^T plane; [2p,3p) xb then Wproj_bf16.
  // d_out (32 MiB): [0,plane) bf16 K plane; [plane,+4194304) bf16 Wqkv chunk
  //   (8 MiB, reused 3x); both dead before proj GEMM overwrites d_out.
  bf16* qw  = (bf16*)d_ws;
  bf16* vtw = qw + plane;
  bf16* xb  = vtw + plane;       // later reused for Wproj bf16
  bf16* kw  = (bf16*)d_out;
  bf16* wqb = kw + plane;        // 2048 rows x 2048 = 8 MiB, fits d_out upper half

  // 1) x -> bf16
  conv_f32_bf16<<<8388608 / 2048, 256, 0, stream>>>(x, xb);
  // 2) QKV GEMM in 3 chunks of N=2048 -> each grid 8x32 = 256 blocks = 1/CU
  //    chunk 0: all Q; chunk 1: all K; chunk 2: all V (transposed scatter)
  for (int chunk = 0; chunk < 3; ++chunk) {
    conv_f32_bf16<<<4194304 / 2048, 256, 0, stream>>>(Wqkv + (size_t)chunk * 4194304, wqb);
    gemm_bt3<0, 1><<<dim3(2048 / 256, Bm / 128), 512, 0, stream>>>(
        xb, wqb, nullptr, qw, kw, vtw, Bm, 2048, E, chunk * 2048);
  }
  // 3) attention (O overwrites Q plane); paired causal 64-row tiles,
  //    512 blocks = 2 independent blocks/CU for TLP
  attn_kernel<<<dim3(16, 32), 256, 0, stream>>>(qw, kw, vtw, 2048);
  // 4) Wproj -> bf16 (xb region; xb dead)
  conv_f32_bf16<<<4194304 / 2048, 256, 0, stream>>>(Wproj, xb);
  // 5) proj GEMM: A = O plane (gather), C = d_out fp32; grid 8x32 = 256 blocks
  gemm_bt3<2, 0><<<dim3(2048 / 256, Bm / 128), 512, 0, stream>>>(
      qw, xb, out, nullptr, nullptr, nullptr, Bm, 2048, E, 0);
}